// Round 2
// baseline (263.370 us; speedup 1.0000x reference)
//
#include <hip/hip_runtime.h>

typedef _Float16 f16;
typedef _Float16 f16x8 __attribute__((ext_vector_type(8)));
typedef float f32x4 __attribute__((ext_vector_type(4)));

static __device__ __forceinline__ f16x8 cvt8(const float4 v0, const float4 v1)
{
    return (f16x8){ (f16)v0.x, (f16)v0.y, (f16)v0.z, (f16)v0.w,
                    (f16)v1.x, (f16)v1.y, (f16)v1.z, (f16)v1.w };
}

// Single fused kernel: one block per (x,y,X,Y); converts its own W-tile
// fp32->f16 into LDS (layout [i][o][quad][8], contiguous ds_write_b128 ->
// zero bank conflicts) and its a/c fragments in registers. No workspace,
// no second dispatch.
// blockIdx swizzle: logical ids 2k/2k+1 (adjacent Y -> adjacent 64B output
// segments of the same 128B line) land on the same XCD so L2 can merge
// full-line writes before HBM eviction.
__global__ __launch_bounds__(256, 5) void rel_fused(
    const float* __restrict__ W,    // (15,15,16,32,32) fp32
    const float* __restrict__ inp,  // (128,8,8,32) fp32
    const float* __restrict__ bias, // (15,15,16) fp32
    float* __restrict__ out)        // (128,8,8,8,8,16) fp32
{
    extern __shared__ __align__(16) f16 Wl[];   // 32768 B exactly -> 5 blocks/CU

    const int hw = blockIdx.x;
    const int bid = ((hw & 7) << 9) | (hw >> 3);   // XCD-paired logical id (bijective)
    const int Y = bid & 7, X = (bid >> 3) & 7, y = (bid >> 6) & 7, x = (bid >> 9) & 7;
    const int dxdy = (X - x + 7) * 15 + (Y - y + 7);

    const int t = threadIdx.x;
    const int lane = t & 63;
    const int wave = t >> 6;       // 0..3 -> b-tiles 2w, 2w+1
    const int quad = lane >> 4;
    const int m = lane & 15;       // A-row (b%16) and B-col (o)

    // ---- stage W-block fp32 -> f16 into LDS, layout [i][o][quad][8] ----
    // granule g -> i=g>>6, o=(g>>2)&15, quad=g&3 ; src = W[dxdy][o][i][quad*8..]
    // chunked (unroll 2) to keep <=~16 VGPRs of load data in flight.
    const float* wsrc = W + (size_t)dxdy * 16384;
    #pragma unroll 2
    for (int it = 0; it < 8; ++it) {
        const int g = it * 256 + t;
        const int gi = g >> 6, go = (g >> 2) & 15, gq = g & 3;
        const float* src = wsrc + go * 1024 + gi * 32 + gq * 8;
        const float4 v0 = *(const float4*)src;
        const float4 v1 = *(const float4*)(src + 4);
        *(f16x8*)(Wl + g * 8) = cvt8(v0, v1);
    }

    // ---- a-rows + c-frags straight from fp32 inp, converted in registers ----
    f16x8 a0[4], a1[4], c0, c1;
    {
        const int b0 = wave * 32 + m, b1 = b0 + 16;
        const float* ar0 = inp + ((b0 * 8 + x) * 8 + y) * 32;
        const float* ar1 = inp + ((b1 * 8 + x) * 8 + y) * 32;
        #pragma unroll 2
        for (int gg = 0; gg < 4; ++gg) {
            a0[gg] = cvt8(*(const float4*)(ar0 + gg * 8),
                          *(const float4*)(ar0 + gg * 8 + 4));
            a1[gg] = cvt8(*(const float4*)(ar1 + gg * 8),
                          *(const float4*)(ar1 + gg * 8 + 4));
        }
        const float* cr0 = inp + ((b0 * 8 + X) * 8 + Y) * 32 + quad * 8;
        const float* cr1 = inp + ((b1 * 8 + X) * 8 + Y) * 32 + quad * 8;
        c0 = cvt8(*(const float4*)cr0, *(const float4*)(cr0 + 4));
        c1 = cvt8(*(const float4*)cr1, *(const float4*)(cr1 + 4));
    }

    __syncthreads();   // ds_write drain + barrier: W-tile ready

    // ---- K-loop: 32 steps (kb = i); explicit 2-deep bfrag prefetch ----
    f32x4 acc0 = {0.f, 0.f, 0.f, 0.f};
    f32x4 acc1 = {0.f, 0.f, 0.f, 0.f};
    const f16* wl = &Wl[m * 32 + quad * 8];
    f16x8 bfrag = *(const f16x8*)(wl);               // kb = 0
    #pragma unroll
    for (int kb = 0; kb < 32; ++kb) {
        const f16x8 bcur = bfrag;
        if (kb < 31)
            bfrag = *(const f16x8*)(wl + (kb + 1) * 512);  // prefetch next
        const f16 av0 = a0[kb >> 3][kb & 7];
        const f16 av1 = a1[kb >> 3][kb & 7];
        const f16x8 af0 = c0 * av0;      // P[b, kb*32 + quad*8 + r]
        const f16x8 af1 = c1 * av1;
        acc0 = __builtin_amdgcn_mfma_f32_16x16x32_f16(af0, bcur, acc0, 0, 0, 0);
        acc1 = __builtin_amdgcn_mfma_f32_16x16x32_f16(af1, bcur, acc1, 0, 0, 0);
    }

    // ---- epilogue: D[row=b%16=quad*4+r, col=o=m] ----
    const float bv = bias[dxdy * 16 + m];
    #pragma unroll
    for (int r = 0; r < 4; ++r) {
        const int b0 = wave * 32 + quad * 4 + r;
        out[((size_t)b0 * 4096 + bid) * 16 + m]        = acc0[r] + bv;
        out[((size_t)(b0 + 16) * 4096 + bid) * 16 + m] = acc1[r] + bv;
    }
}

extern "C" void kernel_launch(void* const* d_in, const int* in_sizes, int n_in,
                              void* d_out, int out_size, void* d_ws, size_t ws_size,
                              hipStream_t stream)
{
    const float* inp  = (const float*)d_in[0];  // (128,8,8,32)
    const float* W    = (const float*)d_in[1];  // (15,15,16,32,32)
    const float* bias = (const float*)d_in[2];  // (15,15,16)
    float* out = (float*)d_out;

    hipLaunchKernelGGL(rel_fused, dim3(4096), dim3(256), 32768, stream,
                       W, inp, bias, out);
}

// Round 3
// 105.581 us; speedup vs baseline: 2.4945x; 2.4945x over previous
//
#include <hip/hip_runtime.h>

typedef _Float16 f16;
typedef _Float16 f16x8 __attribute__((ext_vector_type(8)));
typedef float f32x4 __attribute__((ext_vector_type(4)));
typedef unsigned int u32;
typedef const __attribute__((address_space(1))) u32* gas1_t;
typedef __attribute__((address_space(3))) u32* las3_t;

#define WGRAN 460800   // 225 * 2048 granules of 8 halves (W)
#define IGRAN 32768    // 262144/8 granules (inp)

// fp32 -> f16 with W permuted into the fragment-ready layout:
// W_h[dxdy][i][o][quad] (granules of 8 halves) = W[dxdy][o][i][quad*8+u]
__global__ __launch_bounds__(256) void convert_kernel(
    const float* __restrict__ W, const float* __restrict__ inp,
    f16* __restrict__ W_h, f16* __restrict__ inp_h)
{
    const int g = blockIdx.x * 256 + threadIdx.x;   // grid sized exactly
    if (g < WGRAN) {
        const int dxdy = g >> 11;
        const int r = g & 2047;
        const int i = r >> 6, o = (r >> 2) & 15, quad = r & 3;
        const float* src = W + (size_t)dxdy * 16384 + o * 1024 + i * 32 + quad * 8;
        const float4 v0 = *(const float4*)src;
        const float4 v1 = *(const float4*)(src + 4);
        f16x8 h = { (f16)v0.x, (f16)v0.y, (f16)v0.z, (f16)v0.w,
                    (f16)v1.x, (f16)v1.y, (f16)v1.z, (f16)v1.w };
        *(f16x8*)(W_h + (size_t)g * 8) = h;
    } else {
        const int k = g - WGRAN;
        const float* src = inp + (size_t)k * 8;
        const float4 v0 = *(const float4*)src;
        const float4 v1 = *(const float4*)(src + 4);
        f16x8 h = { (f16)v0.x, (f16)v0.y, (f16)v0.z, (f16)v0.w,
                    (f16)v1.x, (f16)v1.y, (f16)v1.z, (f16)v1.w };
        *(f16x8*)(inp_h + (size_t)k * 8) = h;
    }
}

// One block per (x,y,X,Y), 256 thr = 4 waves, 2 b-tiles per wave.
// LDS layout [i][o][quad][8]: K-loop bfrag wave-read is a contiguous 1024 B
// region per kb -> zero bank conflicts (verified: SQ_LDS_BANK_CONFLICT=0).
// Dynamic LDS of exactly 32768 B -> 5 blocks/CU.
//
// R2 change (single delta vs the 104.6 us baseline): XCD swizzle
//   bid = (hw&7)<<9 | (hw>>3)  ->  x == XCD index (hw%8 round-robin).
// Per-XCD W_h working set = 8 X-values x 15 dy = 120 tiles x 32 KB = 3.84 MB
// < 4 MB L2, visit order (Y fastest, X, y) keeps the active window ~2 MB ->
// W staging becomes an L2-hit stream instead of L3/HBM. Temporally-adjacent
// blocks also have adjacent bid -> adjacent 64 B output segments merge into
// full 128 B lines in L2.
__global__ __launch_bounds__(256, 5) void rel_mfma3(
    const f16* __restrict__ W_h,    // [dxdy][i][o][quad][8]
    const f16* __restrict__ inp_h,  // (128,8,8,32) f16
    const float* __restrict__ bias, // (15,15,16)
    float* __restrict__ out)        // (128,8,8,8,8,16)
{
    extern __shared__ __align__(16) f16 Wl[];   // 32768 B exactly

    const int hw = blockIdx.x;
    const int bid = ((hw & 7) << 9) | (hw >> 3);   // bijective, x = XCD
    const int Y = bid & 7, X = (bid >> 3) & 7, y = (bid >> 6) & 7, x = (bid >> 9) & 7;
    const int dx = X - x + 7, dy = Y - y + 7;
    const int dxdy = dx * 15 + dy;

    const int t = threadIdx.x;

    // ---- stage W-block via global_load_lds width=16 (2048 outstanding DMAs) ----
    {
        const f16* base = W_h + (size_t)dxdy * 16384;
        #pragma unroll
        for (int it = 0; it < 8; ++it) {
            const int idx = (it * 256 + t) * 8;          // 16 B granule
            __builtin_amdgcn_global_load_lds((gas1_t)(base + idx),
                                             (las3_t)&Wl[idx], 16, 0, 0);
        }
    }

    const int lane = t & 63;
    const int wave = t >> 6;       // 0..3 -> b-tiles 2w, 2w+1
    const int quad = lane >> 4;
    const int m = lane & 15;       // A-row (b%16) and B-col (o)

    // ---- a-rows + c-frags from f16 inp (overlap the DMA) ----
    f16x8 a0[4], a1[4], c0, c1;
    {
        const int b0 = wave * 32 + m;
        const int b1 = b0 + 16;
        const f16* ar0 = inp_h + ((b0 * 8 + x) * 8 + y) * 32;
        const f16* ar1 = inp_h + ((b1 * 8 + x) * 8 + y) * 32;
        #pragma unroll
        for (int g = 0; g < 4; ++g) {
            a0[g] = *(const f16x8*)(ar0 + g * 8);
            a1[g] = *(const f16x8*)(ar1 + g * 8);
        }
        c0 = *(const f16x8*)(inp_h + ((b0 * 8 + X) * 8 + Y) * 32 + quad * 8);
        c1 = *(const f16x8*)(inp_h + ((b1 * 8 + X) * 8 + Y) * 32 + quad * 8);
    }

    __syncthreads();   // drains vmcnt -> LDS DMA complete

    // ---- K-loop: 32 steps (kb = i); explicit 2-deep bfrag prefetch ----
    f32x4 acc0 = {0.f, 0.f, 0.f, 0.f};
    f32x4 acc1 = {0.f, 0.f, 0.f, 0.f};
    const f16* wl = &Wl[m * 32 + quad * 8];
    f16x8 bfrag = *(const f16x8*)(wl);               // kb = 0
    #pragma unroll
    for (int kb = 0; kb < 32; ++kb) {
        const f16x8 bcur = bfrag;
        if (kb < 31)
            bfrag = *(const f16x8*)(wl + (kb + 1) * 512);  // prefetch next
        const f16 av0 = a0[kb >> 3][kb & 7];
        const f16 av1 = a1[kb >> 3][kb & 7];
        const f16x8 af0 = c0 * av0;      // P[b, kb*32 + quad*8 + r]
        const f16x8 af1 = c1 * av1;
        acc0 = __builtin_amdgcn_mfma_f32_16x16x32_f16(af0, bcur, acc0, 0, 0, 0);
        acc1 = __builtin_amdgcn_mfma_f32_16x16x32_f16(af1, bcur, acc1, 0, 0, 0);
    }

    // ---- epilogue: D[row=b%16=quad*4+r, col=o=m] ----
    const float bv = bias[dxdy * 16 + m];
    #pragma unroll
    for (int r = 0; r < 4; ++r) {
        const int b0 = wave * 32 + quad * 4 + r;
        out[((size_t)b0 * 4096 + bid) * 16 + m] = acc0[r] + bv;
        out[((size_t)(b0 + 16) * 4096 + bid) * 16 + m] = acc1[r] + bv;
    }
}

extern "C" void kernel_launch(void* const* d_in, const int* in_sizes, int n_in,
                              void* d_out, int out_size, void* d_ws, size_t ws_size,
                              hipStream_t stream)
{
    const float* inp  = (const float*)d_in[0];  // (128,8,8,32)
    const float* W    = (const float*)d_in[1];  // (15,15,16,32,32)
    const float* bias = (const float*)d_in[2];  // (15,15,16)
    float* out = (float*)d_out;

    f16* W_h   = (f16*)d_ws;                         // 7,372,800 halves
    f16* inp_h = (f16*)d_ws + (size_t)WGRAN * 8;     //   262,144 halves

    hipLaunchKernelGGL(convert_kernel, dim3((WGRAN + IGRAN) / 256), dim3(256), 0,
                       stream, W, inp, W_h, inp_h);
    hipLaunchKernelGGL(rel_mfma3, dim3(4096), dim3(256), 32768, stream,
                       W_h, inp_h, bias, out);
}